// Round 5
// baseline (490.635 us; speedup 1.0000x reference)
//
#include <hip/hip_runtime.h>

#define NN 41472
#define NE 829440

typedef __attribute__((ext_vector_type(8))) short short8;
typedef __attribute__((ext_vector_type(4))) float f32x4;
typedef __attribute__((ext_vector_type(4))) float float4v;

// ---- ws layout (bytes): flags@0, fp32 agg@256, MFMA weight frags after ----
#define FLG_OFF   0
#define AGG_OFF   256
#define AGG_BYTES 15925248               // NN*96*4
#define W1F_OFF   (AGG_OFF + AGG_BYTES)  // msg W1: 7ks*6nt*1024B = 43008
#define W2F_OFF   (W1F_OFF + 43008)      // msg W2: 3*6*1024 = 18432
#define W3F_OFF   (W2F_OFF + 18432)
#define P1F_OFF   (W3F_OFF + 18432)      // post W1: 4*6*1024 = 24576
#define P2F_OFF   (P1F_OFF + 24576)
#define P3F_OFF   (P2F_OFF + 18432)
#define IHF_OFF   (P3F_OFF + 18432)      // W_ih: 3*24*1024 = 73728
#define HHF_OFF   (IHF_OFF + 73728)

static __device__ __forceinline__ float bf2f(short s) {
  unsigned u = ((unsigned)(unsigned short)s) << 16;
  return __builtin_bit_cast(float, u);
}
static __device__ __forceinline__ short f2bf(float f) {
  unsigned u = __builtin_bit_cast(unsigned, f);
  unsigned r = (u + 0x7fffu + ((u >> 16) & 1u)) >> 16;
  return (short)r;
}
static __device__ __forceinline__ f32x4 fzero() { f32x4 z = {0.f, 0.f, 0.f, 0.f}; return z; }
static __device__ __forceinline__ short8 szero() { short8 z = {0,0,0,0,0,0,0,0}; return z; }
static __device__ __forceinline__ float sigm(float x) { return 1.f / (1.f + __expf(-x)); }
static __device__ __forceinline__ float tanh_f(float x) {
  float ax = fabsf(x);
  float e  = __expf(-2.f * ax);
  float t  = (1.f - e) / (1.f + e);
  return copysignf(t, x);
}
static __device__ __forceinline__ int clampn(int v) {
  unsigned u = (unsigned)v;
  return (u < (unsigned)NN) ? v : 0;
}
// dtype-adaptive loads (f32=1: fp32 arrays; f32=0: bf16 arrays)
static __device__ __forceinline__ float ldf(const void* base, size_t i, int f32) {
  return f32 ? ((const float*)base)[i] : bf2f(((const short*)base)[i]);
}
static __device__ __forceinline__ short8 ldrow8(const void* base, size_t i, int f32) {
  if (f32) {
    const float* p = (const float*)base + i;
    short8 r;
#pragma unroll
    for (int j = 0; j < 8; ++j) r[j] = f2bf(p[j]);
    return r;
  }
  return *(const short8*)((const short*)base + i);
}
static __device__ __forceinline__ int ldedge(const int* e, int flat, int e64) {
  return e64 ? e[2 * flat] : e[flat];
}

// ---------------- dtype sniffing ----------------
__global__ __launch_bounds__(64) void sniff_kernel(const unsigned* __restrict__ nodes_u,
                                                   const int* __restrict__ edges_i,
                                                   int* __restrict__ flags) {
  if (threadIdx.x != 0) return;
  int votes = 0;
  for (int i = 0; i < 256; ++i) {
    unsigned u = nodes_u[i];
    int ex = (int)((u >> 23) & 0xFFu);
    if (ex >= 116 && ex <= 134) votes++;   // fp32 exponent plausible for N(0,1)
  }
  flags[0] = (votes >= 160) ? 1 : 0;       // 1 => float arrays are fp32
  int z = 0;
  for (int i = 0; i < 128; ++i) if (edges_i[2 * i + 1] == 0) z++;
  flags[1] = (z == 128) ? 1 : 0;           // 1 => edges are int64
}

__global__ __launch_bounds__(256) void zero_agg_kernel(float4v* __restrict__ agg4) {
  agg4[blockIdx.x * 256 + threadIdx.x] = float4v{0.f, 0.f, 0.f, 0.f};
}

// ---------------- weight relayout into MFMA B-fragment layout ----------------
// chunk (ks,nt): elem j of lane l = W[ks*32+(l>>4)*8+j][nt*16+(l&15)]
__global__ __launch_bounds__(64) void relayout_kernel(
    const void* __restrict__ mW1, const void* __restrict__ mW2, const void* __restrict__ mW3,
    const void* __restrict__ pW1, const void* __restrict__ pW2, const void* __restrict__ pW3,
    const void* __restrict__ Wih, const void* __restrict__ Whh, char* __restrict__ ws)
{
  const int f32 = ((const int*)(ws + FLG_OFF))[0];
  int c = blockIdx.x;
  int l = threadIdx.x;
  const void* W; int K, NOUT, NT; size_t off;
  if (c < 42)       { W = mW1; K = 208; NOUT = 96;  NT = 6;  off = W1F_OFF; }
  else if (c < 60)  { c -= 42;  W = mW2; K = 96;  NOUT = 96;  NT = 6;  off = W2F_OFF; }
  else if (c < 78)  { c -= 60;  W = mW3; K = 96;  NOUT = 96;  NT = 6;  off = W3F_OFF; }
  else if (c < 102) { c -= 78;  W = pW1; K = 112; NOUT = 96;  NT = 6;  off = P1F_OFF; }
  else if (c < 120) { c -= 102; W = pW2; K = 96;  NOUT = 96;  NT = 6;  off = P2F_OFF; }
  else if (c < 138) { c -= 120; W = pW3; K = 96;  NOUT = 96;  NT = 6;  off = P3F_OFF; }
  else if (c < 210) { c -= 138; W = Wih; K = 96;  NOUT = 384; NT = 24; off = IHF_OFF; }
  else              { c -= 210; W = Whh; K = 96;  NOUT = 384; NT = 24; off = HHF_OFF; }
  int ks = c / NT, nt = c % NT;
  int lg = l >> 4, lr = l & 15;
  short8 v;
#pragma unroll
  for (int j = 0; j < 8; ++j) {
    int k = ks * 32 + lg * 8 + j;
    int n = nt * 16 + lr;
    v[j] = (k < K) ? f2bf(ldf(W, (size_t)k * NOUT + n, f32)) : (short)0;
  }
  short8* dst = (short8*)(ws + off);
  dst[c * 64 + l] = v;
}

// ---------------- edge message MLP + atomic aggregate ----------------
// 512 threads = 8 waves, 16 edges/wave, 128 edges/block
__global__ __launch_bounds__(512, 2) void edge_kernel(
    const void* __restrict__ nodes, const void* __restrict__ ef,
    const int* __restrict__ edges,
    const void* __restrict__ b1, const void* __restrict__ b2, const void* __restrict__ b3,
    const char* __restrict__ ws, float* __restrict__ agg)
{
  __shared__ __align__(16) short w2f[9216];
  __shared__ __align__(16) short w3f[9216];
  __shared__ __align__(16) short act[8][16][104];

  const int f32 = ((const int*)(ws + FLG_OFF))[0];
  const int e64 = ((const int*)(ws + FLG_OFF))[1];

  {
    const short8* s2 = (const short8*)(ws + W2F_OFF);
    const short8* s3 = (const short8*)(ws + W3F_OFF);
    short8* d2 = (short8*)w2f;
    short8* d3 = (short8*)w3f;
    for (int i = threadIdx.x; i < 1152; i += 512) d2[i] = s2[i];
    for (int i = threadIdx.x; i < 1152; i += 512) d3[i] = s3[i];
  }
  __syncthreads();

  const int wv = threadIdx.x >> 6;
  const int l  = threadIdx.x & 63;
  const int lg = l >> 4, lr = l & 15;
  const int e0 = blockIdx.x * 128 + wv * 16;
  const int eA = e0 + lr;
  const int src = clampn(ldedge(edges, 2 * eA, e64));
  const int dst = clampn(ldedge(edges, 2 * eA + 1, e64));

  const short8* w1g = (const short8*)(ws + W1F_OFF);

  f32x4 acc[6];
#pragma unroll
  for (int nt = 0; nt < 6; ++nt) acc[nt] = fzero();

  // L1: K=208 (src 96 | dst 96 | ef 16 + pad)
#pragma unroll
  for (int ks = 0; ks < 7; ++ks) {
    short8 a;
    if (ks < 3)       a = ldrow8(nodes, (size_t)src * 96 + ks * 32 + lg * 8, f32);
    else if (ks < 6)  a = ldrow8(nodes, (size_t)dst * 96 + (ks - 3) * 32 + lg * 8, f32);
    else if (lg < 2)  a = ldrow8(ef, (size_t)eA * 16 + lg * 8, f32);
    else              a = szero();
#pragma unroll
    for (int nt = 0; nt < 6; ++nt) {
      short8 b = w1g[(ks * 6 + nt) * 64 + l];
      acc[nt] = __builtin_amdgcn_mfma_f32_16x16x32_bf16(a, b, acc[nt], 0, 0, 0);
    }
  }
#pragma unroll
  for (int nt = 0; nt < 6; ++nt) {
    float bb = ldf(b1, nt * 16 + lr, f32);
#pragma unroll
    for (int r = 0; r < 4; ++r) {
      float v = fmaxf(acc[nt][r] + bb, 0.f);
      act[wv][lg * 4 + r][nt * 16 + lr] = f2bf(v);
    }
    acc[nt] = fzero();
  }
  __syncthreads();

  // L2
#pragma unroll
  for (int ks = 0; ks < 3; ++ks) {
    short8 a = *(const short8*)&act[wv][lr][ks * 32 + lg * 8];
#pragma unroll
    for (int nt = 0; nt < 6; ++nt) {
      short8 b = *(const short8*)&w2f[((ks * 6 + nt) * 64 + l) * 8];
      acc[nt] = __builtin_amdgcn_mfma_f32_16x16x32_bf16(a, b, acc[nt], 0, 0, 0);
    }
  }
  __syncthreads();
#pragma unroll
  for (int nt = 0; nt < 6; ++nt) {
    float bb = ldf(b2, nt * 16 + lr, f32);
#pragma unroll
    for (int r = 0; r < 4; ++r) {
      float v = fmaxf(acc[nt][r] + bb, 0.f);
      act[wv][lg * 4 + r][nt * 16 + lr] = f2bf(v);
    }
    acc[nt] = fzero();
  }
  __syncthreads();

  // L3
#pragma unroll
  for (int ks = 0; ks < 3; ++ks) {
    short8 a = *(const short8*)&act[wv][lr][ks * 32 + lg * 8];
#pragma unroll
    for (int nt = 0; nt < 6; ++nt) {
      short8 b = *(const short8*)&w3f[((ks * 6 + nt) * 64 + l) * 8];
      acc[nt] = __builtin_amdgcn_mfma_f32_16x16x32_bf16(a, b, acc[nt], 0, 0, 0);
    }
  }

  int se[4];
#pragma unroll
  for (int r = 0; r < 4; ++r) se[r] = clampn(ldedge(edges, 2 * (e0 + lg * 4 + r), e64));
#pragma unroll
  for (int nt = 0; nt < 6; ++nt) {
    float bb = ldf(b3, nt * 16 + lr, f32);
#pragma unroll
    for (int r = 0; r < 4; ++r) {
      atomicAdd(&agg[(size_t)se[r] * 96 + nt * 16 + lr], acc[nt][r] + bb);
    }
  }
}

// ---------------- node: post-MLP + LSTM (fp32 outputs) ----------------
__global__ __launch_bounds__(512, 1) void node_kernel(
    const float* __restrict__ agg, const void* __restrict__ puzzle,
    const void* __restrict__ h, const void* __restrict__ c,
    const void* __restrict__ pb1, const void* __restrict__ pb2, const void* __restrict__ pb3,
    const void* __restrict__ bih, const void* __restrict__ bhh,
    const char* __restrict__ ws,
    float* __restrict__ oh0, float* __restrict__ oh1, float* __restrict__ oc)
{
  __shared__ __align__(16) short p2f[9216];
  __shared__ __align__(16) short p3f[9216];
  __shared__ __align__(16) short act[8][16][104];

  const int f32 = ((const int*)(ws + FLG_OFF))[0];

  {
    const short8* s2 = (const short8*)(ws + P2F_OFF);
    const short8* s3 = (const short8*)(ws + P3F_OFF);
    short8* d2 = (short8*)p2f;
    short8* d3 = (short8*)p3f;
    for (int i = threadIdx.x; i < 1152; i += 512) d2[i] = s2[i];
    for (int i = threadIdx.x; i < 1152; i += 512) d3[i] = s3[i];
  }
  __syncthreads();

  const int wv = threadIdx.x >> 6;
  const int l  = threadIdx.x & 63;
  const int lg = l >> 4, lr = l & 15;
  const int n0 = blockIdx.x * 128 + wv * 16;
  const int row = n0 + lr;

  const short8* p1g = (const short8*)(ws + P1F_OFF);
  const short8* ihg = (const short8*)(ws + IHF_OFF);
  const short8* hhg = (const short8*)(ws + HHF_OFF);

  f32x4 acc[6];
#pragma unroll
  for (int nt = 0; nt < 6; ++nt) acc[nt] = fzero();

  // post L1: K=96 agg (fp32, hi/lo bf16 split) + 16 puzzle
#pragma unroll
  for (int ks = 0; ks < 3; ++ks) {
    const float* p = agg + (size_t)row * 96 + ks * 32 + lg * 8;
    short8 ahi, alo;
#pragma unroll
    for (int j = 0; j < 8; ++j) {
      float v = p[j];
      short hi = f2bf(v);
      ahi[j] = hi;
      alo[j] = f2bf(v - bf2f(hi));
    }
#pragma unroll
    for (int nt = 0; nt < 6; ++nt) {
      short8 b = p1g[(ks * 6 + nt) * 64 + l];
      acc[nt] = __builtin_amdgcn_mfma_f32_16x16x32_bf16(ahi, b, acc[nt], 0, 0, 0);
      acc[nt] = __builtin_amdgcn_mfma_f32_16x16x32_bf16(alo, b, acc[nt], 0, 0, 0);
    }
  }
  {
    short8 a;
    if (lg < 2) a = ldrow8(puzzle, (size_t)row * 16 + lg * 8, f32);
    else        a = szero();
#pragma unroll
    for (int nt = 0; nt < 6; ++nt) {
      short8 b = p1g[(3 * 6 + nt) * 64 + l];
      acc[nt] = __builtin_amdgcn_mfma_f32_16x16x32_bf16(a, b, acc[nt], 0, 0, 0);
    }
  }
#pragma unroll
  for (int nt = 0; nt < 6; ++nt) {
    float bb = ldf(pb1, nt * 16 + lr, f32);
#pragma unroll
    for (int r = 0; r < 4; ++r) {
      float v = fmaxf(acc[nt][r] + bb, 0.f);
      act[wv][lg * 4 + r][nt * 16 + lr] = f2bf(v);
    }
    acc[nt] = fzero();
  }
  __syncthreads();

  // post L2
#pragma unroll
  for (int ks = 0; ks < 3; ++ks) {
    short8 a = *(const short8*)&act[wv][lr][ks * 32 + lg * 8];
#pragma unroll
    for (int nt = 0; nt < 6; ++nt) {
      short8 b = *(const short8*)&p2f[((ks * 6 + nt) * 64 + l) * 8];
      acc[nt] = __builtin_amdgcn_mfma_f32_16x16x32_bf16(a, b, acc[nt], 0, 0, 0);
    }
  }
  __syncthreads();
#pragma unroll
  for (int nt = 0; nt < 6; ++nt) {
    float bb = ldf(pb2, nt * 16 + lr, f32);
#pragma unroll
    for (int r = 0; r < 4; ++r) {
      float v = fmaxf(acc[nt][r] + bb, 0.f);
      act[wv][lg * 4 + r][nt * 16 + lr] = f2bf(v);
    }
    acc[nt] = fzero();
  }
  __syncthreads();

  // post L3 (no relu) -> x
#pragma unroll
  for (int ks = 0; ks < 3; ++ks) {
    short8 a = *(const short8*)&act[wv][lr][ks * 32 + lg * 8];
#pragma unroll
    for (int nt = 0; nt < 6; ++nt) {
      short8 b = *(const short8*)&p3f[((ks * 6 + nt) * 64 + l) * 8];
      acc[nt] = __builtin_amdgcn_mfma_f32_16x16x32_bf16(a, b, acc[nt], 0, 0, 0);
    }
  }
  __syncthreads();
#pragma unroll
  for (int nt = 0; nt < 6; ++nt) {
    float bb = ldf(pb3, nt * 16 + lr, f32);
#pragma unroll
    for (int r = 0; r < 4; ++r) {
      act[wv][lg * 4 + r][nt * 16 + lr] = f2bf(acc[nt][r] + bb);
    }
  }
  __syncthreads();

  // gates = x@W_ih + h@W_hh ; N-tiles: i=0..5, f=6..11, g=12..17, o=18..23
  f32x4 g[24];
#pragma unroll
  for (int nt = 0; nt < 24; ++nt) g[nt] = fzero();
#pragma unroll
  for (int ks = 0; ks < 3; ++ks) {
    short8 ax = *(const short8*)&act[wv][lr][ks * 32 + lg * 8];
    short8 ah = ldrow8(h, (size_t)row * 96 + ks * 32 + lg * 8, f32);
#pragma unroll
    for (int nt = 0; nt < 24; ++nt) {
      short8 bi = ihg[(ks * 24 + nt) * 64 + l];
      g[nt] = __builtin_amdgcn_mfma_f32_16x16x32_bf16(ax, bi, g[nt], 0, 0, 0);
      short8 bh = hhg[(ks * 24 + nt) * 64 + l];
      g[nt] = __builtin_amdgcn_mfma_f32_16x16x32_bf16(ah, bh, g[nt], 0, 0, 0);
    }
  }

  // LSTM elementwise + fp32 writeback
#pragma unroll
  for (int nt = 0; nt < 6; ++nt) {
    int col = nt * 16 + lr;
    float bi_i = ldf(bih, col, f32)       + ldf(bhh, col, f32);
    float bi_f = ldf(bih, 96 + col, f32)  + ldf(bhh, 96 + col, f32);
    float bi_g = ldf(bih, 192 + col, f32) + ldf(bhh, 192 + col, f32);
    float bi_o = ldf(bih, 288 + col, f32) + ldf(bhh, 288 + col, f32);
#pragma unroll
    for (int r = 0; r < 4; ++r) {
      int node = n0 + lg * 4 + r;
      float iv = g[nt][r]      + bi_i;
      float fv = g[nt + 6][r]  + bi_f;
      float gv = g[nt + 12][r] + bi_g;
      float ov = g[nt + 18][r] + bi_o;
      float cv = ldf(c, (size_t)node * 96 + col, f32);
      float cn = sigm(fv) * cv + sigm(iv) * tanh_f(gv);
      float hn = sigm(ov) * tanh_f(cn);
      oh0[(size_t)node * 96 + col] = hn;
      oh1[(size_t)node * 96 + col] = hn;
      oc [(size_t)node * 96 + col] = cn;
    }
  }
}

// ---------------- output head: out = h_new @ out_W + out_b (fp32) ----------------
__global__ __launch_bounds__(256) void head_kernel(
    const float* __restrict__ hn, const void* __restrict__ oW,
    const void* __restrict__ ob, const char* __restrict__ ws, float* __restrict__ out)
{
  __shared__ __align__(16) float W[960];
  __shared__ __align__(16) float Bb[16];
  const int f32 = ((const int*)(ws + FLG_OFF))[0];
  for (int i = threadIdx.x; i < 960; i += 256) W[i] = ldf(oW, i, f32);
  if (threadIdx.x < 10) Bb[threadIdx.x] = ldf(ob, threadIdx.x, f32);
  __syncthreads();

  int node = blockIdx.x * 256 + threadIdx.x;
  float acc[10];
#pragma unroll
  for (int o = 0; o < 10; ++o) acc[o] = Bb[o];
  for (int k = 0; k < 96; ++k) {
    float hv = hn[(size_t)node * 96 + k];
#pragma unroll
    for (int o = 0; o < 10; ++o) acc[o] = fmaf(hv, W[k * 10 + o], acc[o]);
  }
#pragma unroll
  for (int o = 0; o < 10; ++o) out[(size_t)node * 10 + o] = acc[o];
}

extern "C" void kernel_launch(void* const* d_in, const int* in_sizes, int n_in,
                              void* d_out, int out_size, void* d_ws, size_t ws_size,
                              hipStream_t stream)
{
  const void* puzzle = d_in[0];
  const void* nodes  = d_in[1];
  const void* ef     = d_in[2];
  const void* h      = d_in[3];
  const void* c      = d_in[4];
  const int*  edges  = (const int*)d_in[5];
  const void* mW1 = d_in[6];  const void* mb1 = d_in[7];
  const void* mW2 = d_in[8];  const void* mb2 = d_in[9];
  const void* mW3 = d_in[10]; const void* mb3 = d_in[11];
  const void* pW1 = d_in[12]; const void* pb1 = d_in[13];
  const void* pW2 = d_in[14]; const void* pb2 = d_in[15];
  const void* pW3 = d_in[16]; const void* pb3 = d_in[17];
  const void* Wih = d_in[18]; const void* bih = d_in[19];
  const void* Whh = d_in[20]; const void* bhh = d_in[21];
  const void* oW  = d_in[22]; const void* ob  = d_in[23];

  char*  ws  = (char*)d_ws;
  int* flags = (int*)(ws + FLG_OFF);
  float* agg = (float*)(ws + AGG_OFF);
  float* out = (float*)d_out;
  float* oh0 = out;
  float* oh1 = out + (size_t)NN * 96;
  float* oc  = out + (size_t)2 * NN * 96;
  float* oo  = out + (size_t)3 * NN * 96;

  sniff_kernel<<<1, 64, 0, stream>>>((const unsigned*)nodes, edges, flags);
  zero_agg_kernel<<<3888, 256, 0, stream>>>((float4v*)agg);
  relayout_kernel<<<282, 64, 0, stream>>>(mW1, mW2, mW3, pW1, pW2, pW3, Wih, Whh, ws);
  edge_kernel<<<NE / 128, 512, 0, stream>>>(nodes, ef, edges, mb1, mb2, mb3, ws, agg);
  node_kernel<<<NN / 128, 512, 0, stream>>>(agg, puzzle, h, c, pb1, pb2, pb3, bih, bhh, ws,
                                            oh0, oh1, oc);
  head_kernel<<<NN / 256, 256, 0, stream>>>(oh0, oW, ob, ws, oo);
}